// Round 2
// baseline (1243.952 us; speedup 1.0000x reference)
//
#include <hip/hip_runtime.h>
#include <stdint.h>

#define LOG_N     18
#define N_PER     262144            // 2^18 elements per array (H*W)
#define BATCHES   64
#define TPB       256
#define IPT       16
#define TILE      4096              // TPB * IPT
#define TILES_PER_SEG 64            // N_PER / TILE
#define BINS      256
#define MBLK_PER_BATCH 16
#define MTPB      256
#define MK        128               // merged elems per thread: 2^19/(16*256)

__device__ __forceinline__ uint32_t f2u(float f) {
    uint32_t u = __float_as_uint(f);
    return (u & 0x80000000u) ? ~u : (u | 0x80000000u);
}
__device__ __forceinline__ float u2f(uint32_t x) {
    uint32_t u = (x & 0x80000000u) ? (x ^ 0x80000000u) : ~x;
    return __uint_as_float(u);
}

__global__ void init_losses(double* losses) {
    losses[threadIdx.x] = 0.0;
}

// Per-tile digit histogram. pass 0 reads the raw float inputs (converted).
__global__ __launch_bounds__(TPB) void hist_kernel(
        const float* t1, const float* t2, const uint32_t* src,
        int pass, int base_seg, uint32_t* hist) {
    __shared__ uint32_t h[BINS];
    int tile = blockIdx.x;
    int segL = tile / TILES_PER_SEG;
    int t    = tile % TILES_PER_SEG;
    int shift = pass * 8;
    for (int i = threadIdx.x; i < BINS; i += TPB) h[i] = 0;
    __syncthreads();
    if (pass == 0) {
        int seg = base_seg + segL;
        const float* p = ((seg & 1) ? t2 : t1) + ((size_t)(seg >> 1) << LOG_N) + (size_t)t * TILE;
        for (int k = 0; k < IPT; ++k) {
            uint32_t key = f2u(p[threadIdx.x + k * TPB]);
            atomicAdd(&h[key & 255u], 1u);
        }
    } else {
        const uint32_t* p = src + (size_t)tile * TILE;
        for (int k = 0; k < IPT; ++k) {
            uint32_t key = p[threadIdx.x + k * TPB];
            atomicAdd(&h[(key >> shift) & 255u], 1u);
        }
    }
    __syncthreads();
    for (int i = threadIdx.x; i < BINS; i += TPB)
        hist[(size_t)tile * BINS + i] = h[i];
}

// Per-segment scan: hist[tile][bin] -> within-segment exclusive offsets
// (bin-major over segment, tile-minor within bin). One block per segment.
__global__ __launch_bounds__(BINS) void scan_kernel(uint32_t* hist) {
    __shared__ uint32_t sa[BINS], sb[BINS];
    int segL = blockIdx.x;
    int b = threadIdx.x;
    size_t base = (size_t)segL * TILES_PER_SEG * BINS;
    uint32_t s = 0;
    for (int t = 0; t < TILES_PER_SEG; ++t)
        s += hist[base + (size_t)t * BINS + b];
    sa[b] = s;
    __syncthreads();
    uint32_t* cur = sa; uint32_t* nxt = sb;
    for (int off = 1; off < BINS; off <<= 1) {
        uint32_t v = cur[b] + ((b >= off) ? cur[b - off] : 0u);
        nxt[b] = v;
        __syncthreads();
        uint32_t* tmp = cur; cur = nxt; nxt = tmp;
    }
    uint32_t run = (b == 0) ? 0u : cur[b - 1];
    for (int t = 0; t < TILES_PER_SEG; ++t) {
        size_t idx = base + (size_t)t * BINS + b;
        uint32_t c = hist[idx];
        hist[idx] = run;
        run += c;
    }
}

// Stable scatter: wave ballot-match ranking, LDS reorder, coalesced-ish write.
__global__ __launch_bounds__(TPB) void scatter_kernel(
        const float* t1, const float* t2, const uint32_t* src, uint32_t* dst,
        const uint32_t* scanned, int pass, int base_seg) {
    __shared__ uint32_t whist[4 * BINS];
    __shared__ uint32_t lkeys[TILE];
    __shared__ uint32_t tstart[BINS];
    __shared__ uint32_t gb[BINS];
    __shared__ uint32_t sa[BINS], sb[BINS];

    int tile = blockIdx.x;
    int segL = tile / TILES_PER_SEG;
    int t    = tile % TILES_PER_SEG;
    int shift = pass * 8;
    int tid = threadIdx.x;
    int w = tid >> 6, l = tid & 63;
    uint64_t below = (1ull << l) - 1ull;

    whist[tid] = 0; whist[tid + 256] = 0; whist[tid + 512] = 0; whist[tid + 768] = 0;
    __syncthreads();

    uint32_t keys[IPT];
    uint32_t rnk[IPT];
    const float* p0 = nullptr;
    if (pass == 0) {
        int seg = base_seg + segL;
        p0 = ((seg & 1) ? t2 : t1) + ((size_t)(seg >> 1) << LOG_N) + (size_t)t * TILE;
    }
#pragma unroll
    for (int j = 0; j < IPT; ++j) {
        int posL = w * (64 * IPT) + j * 64 + l;   // tile order: wave-block, iter, lane
        uint32_t key;
        if (pass == 0) key = f2u(p0[posL]);
        else           key = src[(size_t)tile * TILE + posL];
        uint32_t d = (key >> shift) & 255u;
        uint64_t peers = ~0ull;
#pragma unroll
        for (int bb = 0; bb < 8; ++bb) {
            uint64_t m = __ballot((d >> bb) & 1u);
            peers &= ((d >> bb) & 1u) ? m : ~m;
        }
        uint32_t rig = (uint32_t)__popcll(peers & below);
        uint32_t cnt = (uint32_t)__popcll(peers);
        if (rig == 0) whist[w * BINS + d] += cnt;   // one leader per digit-group
        __builtin_amdgcn_wave_barrier();
        uint32_t h = whist[w * BINS + d];           // same-wave DS ops are ordered
        keys[j] = key;
        rnk[j] = h - cnt + rig;                     // stable rank within wave
    }
    __syncthreads();
    {   // wave-exclusive offsets per digit + tile totals + global bases
        int d = tid;
        uint32_t c0 = whist[d], c1 = whist[BINS + d], c2 = whist[2 * BINS + d], c3 = whist[3 * BINS + d];
        whist[d] = 0;
        whist[BINS + d] = c0;
        whist[2 * BINS + d] = c0 + c1;
        whist[3 * BINS + d] = c0 + c1 + c2;
        sa[d] = c0 + c1 + c2 + c3;
        gb[d] = scanned[(size_t)tile * BINS + d];
    }
    __syncthreads();
    {   // exclusive scan of tile digit totals
        int b = tid;
        uint32_t* cur = sa; uint32_t* nxt = sb;
        for (int off = 1; off < BINS; off <<= 1) {
            uint32_t v = cur[b] + ((b >= off) ? cur[b - off] : 0u);
            nxt[b] = v;
            __syncthreads();
            uint32_t* tmp = cur; cur = nxt; nxt = tmp;
        }
        tstart[b] = (b == 0) ? 0u : cur[b - 1];
    }
    __syncthreads();
#pragma unroll
    for (int j = 0; j < IPT; ++j) {
        uint32_t d = (keys[j] >> shift) & 255u;
        uint32_t lp = tstart[d] + whist[w * BINS + d] + rnk[j];
        lkeys[lp] = keys[j];
    }
    __syncthreads();
#pragma unroll
    for (int j = 0; j < IPT; ++j) {
        int i = w * (64 * IPT) + j * 64 + l;
        uint32_t key = lkeys[i];
        uint32_t d = (key >> shift) & 255u;
        uint32_t pos = gb[d] + (uint32_t)i - tstart[d];
        dst[((size_t)segL << LOG_N) + pos] = key;
    }
}

// Merge-path walk over (sorted A, sorted B) per batch, accumulating d^2 * dx.
__global__ __launch_bounds__(MTPB) void integ_kernel(
        const uint32_t* sorted, double* losses, int base_batch) {
    int blk = blockIdx.x;
    int bl  = blk / MBLK_PER_BATCH;
    int pb  = blk % MBLK_PER_BATCH;
    const uint32_t* A = sorted + ((size_t)(2 * bl) << LOG_N);
    const uint32_t* B = A + N_PER;
    const int n = N_PER;
    int p  = pb * MTPB + (int)threadIdx.x;
    int g0 = p * MK;

    // merge-path split (A-first on ties): largest i with A[i-1] <= B[g0-i]
    int lo = g0 - n; if (lo < 0) lo = 0;
    int hi = g0 < n ? g0 : n;
    while (lo < hi) {
        int mid = (lo + hi + 1) >> 1;
        if (A[mid - 1] <= B[g0 - mid]) lo = mid; else hi = mid - 1;
    }
    int i = lo, j = g0 - lo;

    int steps = 2 * n - 1 - g0; if (steps > MK) steps = MK;

    uint32_t ca = (i < n) ? A[i] : 0xFFFFFFFFu;
    uint32_t cb = (j < n) ? B[j] : 0xFFFFFFFFu;
    uint32_t prev;
    if (ca <= cb) { prev = ca; ++i; ca = (i < n) ? A[i] : 0xFFFFFFFFu; }
    else          { prev = cb; ++j; cb = (j < n) ? B[j] : 0xFFFFFFFFu; }
    int d = i - j;
    double acc = 0.0;
    for (int s = 0; s < steps; ++s) {
        bool ta = (ca <= cb);
        uint32_t nxt = ta ? ca : cb;
        float delta = u2f(nxt) - u2f(prev);           // fp32 diff, like reference
        acc += (double)d * (double)d * (double)delta;
        if (ta) { ++i; ca = (i < n) ? A[i] : 0xFFFFFFFFu; }
        else    { ++j; cb = (j < n) ? B[j] : 0xFFFFFFFFu; }
        d = i - j;
        prev = nxt;
    }

    __shared__ double red[MTPB];
    red[threadIdx.x] = acc;
    __syncthreads();
    for (int off = MTPB / 2; off > 0; off >>= 1) {
        if ((int)threadIdx.x < off) red[threadIdx.x] += red[threadIdx.x + off];
        __syncthreads();
    }
    if (threadIdx.x == 0) atomicAdd(&losses[base_batch + bl], red[0]);
}

__global__ void final_kernel(const double* losses, float* out) {
    int tid = threadIdx.x;   // 64 threads
    const double inv = 1.0 / ((double)N_PER * (double)N_PER);
    double loss = sqrt(losses[tid] * inv);
    for (int off = 32; off > 0; off >>= 1)
        loss += __shfl_down(loss, off);
    if (tid == 0) out[0] = (float)(loss / (double)BATCHES);
}

extern "C" void kernel_launch(void* const* d_in, const int* in_sizes, int n_in,
                              void* d_out, int out_size, void* d_ws, size_t ws_size,
                              hipStream_t stream) {
    const float* t1 = (const float*)d_in[0];
    const float* t2 = (const float*)d_in[1];
    float* out = (float*)d_out;

    char* ws = (char*)d_ws;
    double* losses = (double*)ws;
    size_t off = 1024;
    size_t perBatchKeys = (size_t)2 << LOG_N;                 // 2^19 keys
    size_t perBatchBuf  = perBatchKeys * 4;                   // 2 MB
    size_t perBatchHist = (size_t)2 * TILES_PER_SEG * BINS * 4; // 128 KB
    size_t perBatch = 2 * perBatchBuf + perBatchHist;

    // Guard: never run with an overflowing workspace (clean failure > GPU fault)
    if (ws_size < off + perBatch) return;

    int CB = (int)((ws_size - off) / perBatch);
    if (CB > BATCHES) CB = BATCHES;
    uint32_t* bufA = (uint32_t*)(ws + off);
    uint32_t* bufB = bufA + (size_t)CB * perBatchKeys;
    uint32_t* hist = (uint32_t*)(bufB + (size_t)CB * perBatchKeys);

    hipLaunchKernelGGL(init_losses, dim3(1), dim3(BATCHES), 0, stream, losses);

    for (int base = 0; base < BATCHES; base += CB) {
        int nb = BATCHES - base < CB ? BATCHES - base : CB;
        int nseg = 2 * nb;
        int ntile = nseg * TILES_PER_SEG;
        const uint32_t* src = nullptr;
        uint32_t* dst = bufA;
        for (int pass = 0; pass < 4; ++pass) {
            hipLaunchKernelGGL(hist_kernel, dim3(ntile), dim3(TPB), 0, stream,
                               t1, t2, src, pass, 2 * base, hist);
            hipLaunchKernelGGL(scan_kernel, dim3(nseg), dim3(BINS), 0, stream, hist);
            hipLaunchKernelGGL(scatter_kernel, dim3(ntile), dim3(TPB), 0, stream,
                               t1, t2, src, dst, hist, pass, 2 * base);
            src = dst;
            dst = (dst == bufA) ? bufB : bufA;
        }
        hipLaunchKernelGGL(integ_kernel, dim3(nb * MBLK_PER_BATCH), dim3(MTPB), 0, stream,
                           src, losses, base);
    }
    hipLaunchKernelGGL(final_kernel, dim3(1), dim3(BATCHES), 0, stream, losses, out);
}

// Round 3
// 770.133 us; speedup vs baseline: 1.6152x; 1.6152x over previous
//
#include <hip/hip_runtime.h>
#include <stdint.h>

#define LOG_N     18
#define N_PER     262144            // 2^18 elements per array (H*W)
#define BATCHES   64
#define TPB       256
#define IPT       16
#define TILE      4096              // TPB * IPT
#define TILES_PER_SEG 64            // N_PER / TILE
#define BINS      256

#define ITPB      256               // integ threads per block
#define TPM       32                // merged elements per thread
#define IBLK      (ITPB * TPM)      // 8192 merged elements per block
#define IBPB      ((2 * N_PER) / IBLK) // 64 blocks per batch

__device__ __forceinline__ uint32_t f2u(float f) {
    uint32_t u = __float_as_uint(f);
    return (u & 0x80000000u) ? ~u : (u | 0x80000000u);
}
__device__ __forceinline__ float u2f(uint32_t x) {
    uint32_t u = (x & 0x80000000u) ? (x ^ 0x80000000u) : ~x;
    return __uint_as_float(u);
}

__global__ void init_losses(double* losses) {
    losses[threadIdx.x] = 0.0;
}

// Per-tile digit histogram. pass 0 reads the raw float inputs (converted).
__global__ __launch_bounds__(TPB) void hist_kernel(
        const float* t1, const float* t2, const uint32_t* src,
        int pass, int base_seg, uint32_t* hist) {
    __shared__ uint32_t h[BINS];
    int tile = blockIdx.x;
    int segL = tile / TILES_PER_SEG;
    int t    = tile % TILES_PER_SEG;
    int shift = pass * 8;
    for (int i = threadIdx.x; i < BINS; i += TPB) h[i] = 0;
    __syncthreads();
    if (pass == 0) {
        int seg = base_seg + segL;
        const float4* p = (const float4*)(((seg & 1) ? t2 : t1) + ((size_t)(seg >> 1) << LOG_N) + (size_t)t * TILE);
        for (int k = 0; k < IPT / 4; ++k) {
            float4 v = p[threadIdx.x + k * TPB];
            atomicAdd(&h[f2u(v.x) & 255u], 1u);
            atomicAdd(&h[f2u(v.y) & 255u], 1u);
            atomicAdd(&h[f2u(v.z) & 255u], 1u);
            atomicAdd(&h[f2u(v.w) & 255u], 1u);
        }
    } else {
        const uint4* p = (const uint4*)(src + (size_t)tile * TILE);
        for (int k = 0; k < IPT / 4; ++k) {
            uint4 v = p[threadIdx.x + k * TPB];
            atomicAdd(&h[(v.x >> shift) & 255u], 1u);
            atomicAdd(&h[(v.y >> shift) & 255u], 1u);
            atomicAdd(&h[(v.z >> shift) & 255u], 1u);
            atomicAdd(&h[(v.w >> shift) & 255u], 1u);
        }
    }
    __syncthreads();
    for (int i = threadIdx.x; i < BINS; i += TPB)
        hist[(size_t)tile * BINS + i] = h[i];
}

// Per-segment scan: hist[tile][bin] -> within-segment exclusive offsets
// (bin-major over segment, tile-minor within bin). One block per segment.
__global__ __launch_bounds__(BINS) void scan_kernel(uint32_t* hist) {
    __shared__ uint32_t sa[BINS], sb[BINS];
    int segL = blockIdx.x;
    int b = threadIdx.x;
    size_t base = (size_t)segL * TILES_PER_SEG * BINS;
    uint32_t s = 0;
#pragma unroll 8
    for (int t = 0; t < TILES_PER_SEG; ++t)
        s += hist[base + (size_t)t * BINS + b];
    sa[b] = s;
    __syncthreads();
    uint32_t* cur = sa; uint32_t* nxt = sb;
    for (int off = 1; off < BINS; off <<= 1) {
        uint32_t v = cur[b] + ((b >= off) ? cur[b - off] : 0u);
        nxt[b] = v;
        __syncthreads();
        uint32_t* tmp = cur; cur = nxt; nxt = tmp;
    }
    uint32_t run = (b == 0) ? 0u : cur[b - 1];
#pragma unroll 8
    for (int t = 0; t < TILES_PER_SEG; ++t) {
        size_t idx = base + (size_t)t * BINS + b;
        uint32_t c = hist[idx];
        hist[idx] = run;
        run += c;
    }
}

// Stable scatter: wave ballot-match ranking, LDS reorder, coalesced-ish write.
__global__ __launch_bounds__(TPB) void scatter_kernel(
        const float* t1, const float* t2, const uint32_t* src, uint32_t* dst,
        const uint32_t* scanned, int pass, int base_seg) {
    __shared__ uint32_t whist[4 * BINS];
    __shared__ uint32_t lkeys[TILE];
    __shared__ uint32_t tstart[BINS];
    __shared__ uint32_t gb[BINS];
    __shared__ uint32_t sa[BINS], sb[BINS];

    int tile = blockIdx.x;
    int segL = tile / TILES_PER_SEG;
    int t    = tile % TILES_PER_SEG;
    int shift = pass * 8;
    int tid = threadIdx.x;
    int w = tid >> 6, l = tid & 63;
    uint64_t below = (1ull << l) - 1ull;

    whist[tid] = 0; whist[tid + 256] = 0; whist[tid + 512] = 0; whist[tid + 768] = 0;
    __syncthreads();

    uint32_t keys[IPT];
    uint32_t rnk[IPT];
    const float* p0 = nullptr;
    if (pass == 0) {
        int seg = base_seg + segL;
        p0 = ((seg & 1) ? t2 : t1) + ((size_t)(seg >> 1) << LOG_N) + (size_t)t * TILE;
    }
#pragma unroll
    for (int j = 0; j < IPT; ++j) {
        int posL = w * (64 * IPT) + j * 64 + l;   // tile order: wave-block, iter, lane
        uint32_t key;
        if (pass == 0) key = f2u(p0[posL]);
        else           key = src[(size_t)tile * TILE + posL];
        uint32_t d = (key >> shift) & 255u;
        uint64_t peers = ~0ull;
#pragma unroll
        for (int bb = 0; bb < 8; ++bb) {
            uint64_t m = __ballot((d >> bb) & 1u);
            peers &= ((d >> bb) & 1u) ? m : ~m;
        }
        uint32_t rig = (uint32_t)__popcll(peers & below);
        uint32_t cnt = (uint32_t)__popcll(peers);
        if (rig == 0) whist[w * BINS + d] += cnt;   // one leader per digit-group
        __builtin_amdgcn_wave_barrier();
        uint32_t h = whist[w * BINS + d];           // same-wave DS ops are ordered
        keys[j] = key;
        rnk[j] = h - cnt + rig;                     // stable rank within wave
    }
    __syncthreads();
    {   // wave-exclusive offsets per digit + tile totals + global bases
        int d = tid;
        uint32_t c0 = whist[d], c1 = whist[BINS + d], c2 = whist[2 * BINS + d], c3 = whist[3 * BINS + d];
        whist[d] = 0;
        whist[BINS + d] = c0;
        whist[2 * BINS + d] = c0 + c1;
        whist[3 * BINS + d] = c0 + c1 + c2;
        sa[d] = c0 + c1 + c2 + c3;
        gb[d] = scanned[(size_t)tile * BINS + d];
    }
    __syncthreads();
    {   // exclusive scan of tile digit totals
        int b = tid;
        uint32_t* cur = sa; uint32_t* nxt = sb;
        for (int off = 1; off < BINS; off <<= 1) {
            uint32_t v = cur[b] + ((b >= off) ? cur[b - off] : 0u);
            nxt[b] = v;
            __syncthreads();
            uint32_t* tmp = cur; cur = nxt; nxt = tmp;
        }
        tstart[b] = (b == 0) ? 0u : cur[b - 1];
    }
    __syncthreads();
#pragma unroll
    for (int j = 0; j < IPT; ++j) {
        uint32_t d = (keys[j] >> shift) & 255u;
        uint32_t lp = tstart[d] + whist[w * BINS + d] + rnk[j];
        lkeys[lp] = keys[j];
    }
    __syncthreads();
#pragma unroll
    for (int j = 0; j < IPT; ++j) {
        int i = w * (64 * IPT) + j * 64 + l;
        uint32_t key = lkeys[i];
        uint32_t d = (key >> shift) & 255u;
        uint32_t pos = gb[d] + (uint32_t)i - tstart[d];
        dst[((size_t)segL << LOG_N) + pos] = key;
    }
}

// LDS merge-path integration: block stages its exact A/B ranges into LDS
// (coalesced), then each thread merge-walks TPM elements out of LDS,
// accumulating d^2 * dx.
__global__ __launch_bounds__(ITPB) void integ_kernel(
        const uint32_t* sorted, double* losses, int base_batch) {
    __shared__ uint32_t lbuf[IBLK + 4];
    __shared__ double red[ITPB];

    int blk = blockIdx.x;
    int bl  = blk / IBPB;
    int pb  = blk % IBPB;
    const uint32_t* A = sorted + ((size_t)(2 * bl) << LOG_N);
    const uint32_t* B = A + N_PER;
    const int n = N_PER;
    int g0 = pb * IBLK;
    int g1 = g0 + IBLK;

    // global merge-path splits (redundant across threads; same-address loads broadcast)
    int ia0, ia1;
    {
        int lo = g0 - n; if (lo < 0) lo = 0;
        int hi = g0 < n ? g0 : n;
        while (lo < hi) { int mid = (lo + hi + 1) >> 1; if (A[mid - 1] <= B[g0 - mid]) lo = mid; else hi = mid - 1; }
        ia0 = lo;
    }
    {
        int lo = g1 - n; if (lo < 0) lo = 0;
        int hi = g1 < n ? g1 : n;
        while (lo < hi) { int mid = (lo + hi + 1) >> 1; if (A[mid - 1] <= B[g1 - mid]) lo = mid; else hi = mid - 1; }
        ia1 = lo;
    }
    int jb0 = g0 - ia0, jb1 = g1 - ia1;
    int nA = ia1 - ia0, nB = jb1 - jb0;

    uint32_t* lA = lbuf;            // lA[0..nA]   (sentinel at nA = true next A or INF)
    uint32_t* lB = lbuf + nA + 1;   // lB[0..nB]   (sentinel at nB = true next B or INF)
    for (int k = threadIdx.x; k <= nA; k += ITPB) {
        int gi = ia0 + k;
        lA[k] = (gi < n) ? A[gi] : 0xFFFFFFFFu;
    }
    for (int k = threadIdx.x; k <= nB; k += ITPB) {
        int gj = jb0 + k;
        lB[k] = (gj < n) ? B[gj] : 0xFFFFFFFFu;
    }
    __syncthreads();

    // local merge-path split for this thread's start
    int t0 = (int)threadIdx.x * TPM;
    int lo = t0 - nB; if (lo < 0) lo = 0;
    int hi = t0 < nA ? t0 : nA;
    while (lo < hi) { int mid = (lo + hi + 1) >> 1; if (lA[mid - 1] <= lB[t0 - mid]) lo = mid; else hi = mid - 1; }
    int li = lo, lj = t0 - lo;

    int p0 = g0 + t0;
    int steps = 2 * n - 1 - p0; if (steps > TPM) steps = TPM;

    uint32_t ca = lA[li], cb = lB[lj];
    uint32_t prev;
    if (ca <= cb) { prev = ca; ++li; ca = lA[li]; }
    else          { prev = cb; ++lj; cb = lB[lj]; }
    int d = (ia0 + li) - (jb0 + lj);
    double acc = 0.0;
    for (int s = 0; s < steps; ++s) {
        bool ta = (ca <= cb);
        uint32_t nxt = ta ? ca : cb;
        float delta = u2f(nxt) - u2f(prev);           // fp32 diff, like reference
        double dd = (double)d;
        acc += dd * dd * (double)delta;
        if (ta) { ++li; ca = lA[li]; ++d; }
        else    { ++lj; cb = lB[lj]; --d; }
        prev = nxt;
    }

    red[threadIdx.x] = acc;
    __syncthreads();
    for (int off = ITPB / 2; off > 0; off >>= 1) {
        if ((int)threadIdx.x < off) red[threadIdx.x] += red[threadIdx.x + off];
        __syncthreads();
    }
    if (threadIdx.x == 0) atomicAdd(&losses[base_batch + bl], red[0]);
}

__global__ void final_kernel(const double* losses, float* out) {
    int tid = threadIdx.x;   // 64 threads
    const double inv = 1.0 / ((double)N_PER * (double)N_PER);
    double loss = sqrt(losses[tid] * inv);
    for (int off = 32; off > 0; off >>= 1)
        loss += __shfl_down(loss, off);
    if (tid == 0) out[0] = (float)(loss / (double)BATCHES);
}

extern "C" void kernel_launch(void* const* d_in, const int* in_sizes, int n_in,
                              void* d_out, int out_size, void* d_ws, size_t ws_size,
                              hipStream_t stream) {
    const float* t1 = (const float*)d_in[0];
    const float* t2 = (const float*)d_in[1];
    float* out = (float*)d_out;

    char* ws = (char*)d_ws;
    double* losses = (double*)ws;
    size_t off = 1024;
    size_t perBatchKeys = (size_t)2 << LOG_N;                 // 2^19 keys
    size_t perBatchBuf  = perBatchKeys * 4;                   // 2 MB
    size_t perBatchHist = (size_t)2 * TILES_PER_SEG * BINS * 4; // 128 KB
    size_t perBatch = 2 * perBatchBuf + perBatchHist;

    // Guard: never run with an overflowing workspace (clean failure > GPU fault)
    if (ws_size < off + perBatch) return;

    int CB = (int)((ws_size - off) / perBatch);
    if (CB > BATCHES) CB = BATCHES;
    uint32_t* bufA = (uint32_t*)(ws + off);
    uint32_t* bufB = bufA + (size_t)CB * perBatchKeys;
    uint32_t* hist = (uint32_t*)(bufB + (size_t)CB * perBatchKeys);

    hipLaunchKernelGGL(init_losses, dim3(1), dim3(BATCHES), 0, stream, losses);

    for (int base = 0; base < BATCHES; base += CB) {
        int nb = BATCHES - base < CB ? BATCHES - base : CB;
        int nseg = 2 * nb;
        int ntile = nseg * TILES_PER_SEG;
        const uint32_t* src = nullptr;
        uint32_t* dst = bufA;
        for (int pass = 0; pass < 4; ++pass) {
            hipLaunchKernelGGL(hist_kernel, dim3(ntile), dim3(TPB), 0, stream,
                               t1, t2, src, pass, 2 * base, hist);
            hipLaunchKernelGGL(scan_kernel, dim3(nseg), dim3(BINS), 0, stream, hist);
            hipLaunchKernelGGL(scatter_kernel, dim3(ntile), dim3(TPB), 0, stream,
                               t1, t2, src, dst, hist, pass, 2 * base);
            src = dst;
            dst = (dst == bufA) ? bufB : bufA;
        }
        hipLaunchKernelGGL(integ_kernel, dim3(nb * IBPB), dim3(ITPB), 0, stream,
                           src, losses, base);
    }
    hipLaunchKernelGGL(final_kernel, dim3(1), dim3(BATCHES), 0, stream, losses, out);
}